// Round 10
// baseline (335.985 us; speedup 1.0000x reference)
//
#include <hip/hip_runtime.h>
#include <math.h>

typedef unsigned short u16;
typedef unsigned int   u32;
typedef __attribute__((ext_vector_type(4))) float f32x4;   // native vec for nontemporal

// ---------------- scratch layout (fp32 offsets in d_ws; ws ~868 MB) ----------
#define OFF_AT    0          // |analytic|, [16][32768] (transposed)  524288 f
#define OFF_PT    524288     // angle,      [16][32768]               524288 f
#define OFF_WT    1048576    // W_sindy^T (deg1 folded), [1016][16]   16256 f
#define OFF_ZT    1064832    // z transposed [16][32768]              524288 f
#define OFF_TWC   1589120    // 1024 doubles (cos) = 2048 f
#define OFF_TWS   1591168    // 1024 doubles (sin)

// jac f4 ranges per kernel (exactly tile [0, 16777216)); all LO % 512 == 0
#define R1_LO 0
#define R1_HI 5592576
#define R2_LO 5592576
#define R2_HI 11185152
#define R3_LO 11185152
#define R3_HI 16777216

// jac[b,t,l,f] = W_enc[l,f]: flat f4 index i sources Wenc f4 (i & 511).
// Requires nth % 512 == 0 so the source index is loop-invariant.
__device__ __forceinline__ void jac_range(const float* __restrict__ Wenc,
                                          float* __restrict__ out_jac,
                                          int lo, int hi, int idx, int nth)
{
    const float* wsrc = Wenc + (size_t)((lo + idx) & 511) * 4;
    f32x4 w;
    w.x = wsrc[0]; w.y = wsrc[1]; w.z = wsrc[2]; w.w = wsrc[3];
    f32x4* j4 = (f32x4*)out_jac;
    for (int i = lo + idx; i < hi; i += nth)
        __builtin_nontemporal_store(w, j4 + i);
}

// ======================================================================
// K1: encoder + decoder (R3/R9-proven form, byte-identical).
// ======================================================================
__global__ __launch_bounds__(256) void k1_encdec(
    const float* __restrict__ x, const float* __restrict__ Wenc, const float* __restrict__ benc,
    const float* __restrict__ Wdec, const float* __restrict__ bdec,
    const float* __restrict__ Wsin,
    float* __restrict__ out_z, float* __restrict__ out_xhat,
    float* __restrict__ out_Ws, float* __restrict__ out_Wd,
    float* __restrict__ z_t, float* __restrict__ wt,
    double* __restrict__ twc_g, double* __restrict__ tws_g,
    float* __restrict__ out_jac)
{
    int tid = threadIdx.x;
    int blk = blockIdx.x;

    if (blk >= 1092) {       // 1024 writer blocks, nth = 262144 (512 | nth)
        jac_range(Wenc, out_jac, R1_LO, R1_HI, (blk - 1092) * 256 + tid, 262144);
        return;
    }
    if (blk >= 1024) {
        int t0 = (blk - 1024) * 256 + tid;   // 68 blocks -> 17408 threads
        if (t0 < 16256) {
            float v = Wsin[t0];
            out_Ws[t0] = v;                  // pass-through: ORIGINAL value
            int l = t0 / 1016;
            int d = t0 - l * 1016;
            // fold z-dup feature (968+d) into deg-1 row d
            if (d < 16) v += Wsin[t0 + 968];
            wt[d * 16 + l] = v;
        } else if (t0 < 17280) {             // 1024 twiddles, fp64, once
            int k = t0 - 16256;
            double ang = -6.283185307179586476925286766559 * (double)k / 2048.0;
            double s_, c_;
            sincos(ang, &s_, &c_);
            twc_g[k] = c_;
            tws_g[k] = s_;
        }
        if (t0 < 2048) out_Wd[t0] = Wdec[t0];
        return;
    }

    __shared__ float xs[32][132];   // 16896 B, f4 row stride 33 (conflict-free)
    __shared__ float we[16][132];   //  8448 B
    __shared__ float wdT[16][132];  //  8448 B (wd transposed: wdT[l][f])
    __shared__ float zs[32][20];    //  2560 B (f4-aligned rows: 80 B)

    {   // stage x: 1024 float4, coalesced
        const float4* xv = (const float4*)x + (size_t)blk * 1024;
        float4* xs4 = (float4*)&xs[0][0];
        #pragma unroll
        for (int h = 0; h < 4; ++h) {
            int vi = tid + h * 256;
            int pt = vi >> 5, fq = vi & 31;
            xs4[pt * 33 + fq] = xv[vi];
        }
    }
    {   // stage we: 512 float4
        const float4* wev = (const float4*)Wenc;
        float4* we4 = (float4*)&we[0][0];
        #pragma unroll
        for (int h = 0; h < 2; ++h) {
            int vi = tid + h * 256;
            int l = vi >> 5, fq = vi & 31;
            we4[l * 33 + fq] = wev[vi];
        }
    }
    {   // stage wdT (transpose scatter, one-time)
        const float4* wdv = (const float4*)Wdec;
        #pragma unroll
        for (int h = 0; h < 2; ++h) {
            int vi = tid + h * 256;
            float4 v = wdv[vi];
            int f = vi >> 2, lq = (vi & 3) * 4;
            wdT[lq + 0][f] = v.x; wdT[lq + 1][f] = v.y;
            wdT[lq + 2][f] = v.z; wdT[lq + 3][f] = v.w;
        }
    }
    __syncthreads();

    {   // encoder: thread (pt = tid>>3, lp = tid&7) -> l = lp and lp+8
        int pt = tid >> 3, lp = tid & 7;
        const float4* xr = (const float4*)&xs[pt][0];
        const float4* wa = (const float4*)&we[lp][0];
        const float4* wb = (const float4*)&we[lp + 8][0];
        float s0 = 0.f, s1 = 0.f;
        #pragma unroll 8
        for (int fq = 0; fq < 32; ++fq) {
            float4 a = xr[fq], u = wa[fq], v = wb[fq];
            s0 = fmaf(a.x, u.x, s0); s0 = fmaf(a.y, u.y, s0);
            s0 = fmaf(a.z, u.z, s0); s0 = fmaf(a.w, u.w, s0);
            s1 = fmaf(a.x, v.x, s1); s1 = fmaf(a.y, v.y, s1);
            s1 = fmaf(a.z, v.z, s1); s1 = fmaf(a.w, v.w, s1);
        }
        zs[pt][lp]     = s0 + benc[lp];
        zs[pt][lp + 8] = s1 + benc[lp + 8];
    }
    __syncthreads();

    {   // out_z (dense coalesced) + z_t (transposed, 32-float runs)
        #pragma unroll
        for (int h = 0; h < 2; ++h) {
            int i = tid + h * 256;
            out_z[(size_t)blk * 512 + i] = zs[i >> 4][i & 15];
        }
        #pragma unroll
        for (int h = 0; h < 2; ++h) {
            int i = tid + h * 256;
            int l = i >> 5, pt = i & 31;
            z_t[(size_t)l * 32768 + blk * 32 + pt] = zs[pt][l];
        }
    }

    {   // decoder: thread (f = tid&127, half = tid>>7) -> 16 points
        int f = tid & 127, half = tid >> 7;
        float w[16];
        #pragma unroll
        for (int l = 0; l < 16; ++l) w[l] = wdT[l][f];
        float bd = bdec[f];
        #pragma unroll
        for (int p = 0; p < 16; ++p) {
            int pt = half * 16 + p;
            const float4* zr = (const float4*)&zs[pt][0];
            float4 z0 = zr[0], z1 = zr[1], z2 = zr[2], z3 = zr[3];
            float acc = bd;
            acc = fmaf(z0.x, w[0],  acc); acc = fmaf(z0.y, w[1],  acc);
            acc = fmaf(z0.z, w[2],  acc); acc = fmaf(z0.w, w[3],  acc);
            acc = fmaf(z1.x, w[4],  acc); acc = fmaf(z1.y, w[5],  acc);
            acc = fmaf(z1.z, w[6],  acc); acc = fmaf(z1.w, w[7],  acc);
            acc = fmaf(z2.x, w[8],  acc); acc = fmaf(z2.y, w[9],  acc);
            acc = fmaf(z2.z, w[10], acc); acc = fmaf(z2.w, w[11], acc);
            acc = fmaf(z3.x, w[12], acc); acc = fmaf(z3.y, w[13], acc);
            acc = fmaf(z3.z, w[14], acc); acc = fmaf(z3.w, w[15], acc);
            out_xhat[(size_t)blk * 4096 + (size_t)pt * 128 + f] = acc;
        }
    }
}

// ======================================================================
// K2: Hilbert per (b,l), fp64 LDS FFT (R3/R9-proven form, byte-identical).
//     Blocks >=256: jac range R2.
// ======================================================================
#define TWPAD(k) ((k) + ((k) >> 5))
#define CP(i)    ((i) + ((i) >> 4))

__global__ __launch_bounds__(1024) void k2_hilbert(
    const float* __restrict__ z_t, const double* __restrict__ twc_g,
    const double* __restrict__ tws_g, const float* __restrict__ Wenc,
    float* __restrict__ a_t, float* __restrict__ p_t,
    float* __restrict__ out_jac)
{
    __shared__ double2 c[2176];     // CP(2047)=2174 -> 2176; 34816 B
    __shared__ double twc_s[1056];  // TWPAD(1023)=1054 -> 1056; 8448 B
    __shared__ double tws_s[1056];  // 8448 B  (total 51712 B)

    int tid = threadIdx.x;
    if (blockIdx.x >= 256) {       // 512 writer blocks, nth = 524288
        jac_range(Wenc, out_jac, R2_LO, R2_HI, (blockIdx.x - 256) * 1024 + tid, 524288);
        return;
    }
    int b = blockIdx.x >> 4, l = blockIdx.x & 15;
    const size_t base = (size_t)l * 32768 + (size_t)b * 2048;
    const float* zp = z_t + base;

    {
        twc_s[TWPAD(tid)] = twc_g[tid];
        tws_s[TWPAD(tid)] = tws_g[tid];
    }
    {
        double2 v0; v0.x = (double)zp[tid];        v0.y = 0.0;
        double2 v1; v1.x = (double)zp[tid + 1024]; v1.y = 0.0;
        c[CP(tid)] = v0;
        c[CP(tid + 1024)] = v1;
    }
    __syncthreads();

    // forward DIF: u'=u+v, v'=(u-v)*W^(j*step)
    for (int half = 1024; half >= 1; half >>= 1) {
        int step = 1024 / half;
        int j = tid & (half - 1);
        int pos = ((tid - j) << 1) + j;
        int pa = CP(pos), pb = CP(pos + half);
        int ti = TWPAD(j * step);
        double2 u = c[pa], v = c[pb];
        double wc = twc_s[ti], wsn = tws_s[ti];
        double2 s, dsc;
        s.x = u.x + v.x;  s.y = u.y + v.y;
        double br = u.x - v.x, bi = u.y - v.y;
        dsc.x = br * wc - bi * wsn;
        dsc.y = br * wsn + bi * wc;
        c[pa] = s;
        c[pb] = dsc;
        __syncthreads();
    }

    // Hilbert filter in bitrev domain (k==0 <-> p==0, k>=1024 <-> p odd), 1/N folded
    #pragma unroll
    for (int h = 0; h < 2; ++h) {
        int t = tid + h * 1024;
        double sc = (t == 0 || (t & 1)) ? 0.0 : (2.0 / 2048.0);
        int ci = CP(t);
        double2 v = c[ci];
        v.x *= sc; v.y *= sc;
        c[ci] = v;
    }
    __syncthreads();

    // inverse DIT: t = v*conj(W); u'=u+t, v'=u-t
    for (int half = 1; half <= 1024; half <<= 1) {
        int step = 1024 / half;
        int j = tid & (half - 1);
        int pos = ((tid - j) << 1) + j;
        int pa = CP(pos), pb = CP(pos + half);
        int ti = TWPAD(j * step);
        double2 u = c[pa], v = c[pb];
        double wc = twc_s[ti], wsn = tws_s[ti];
        double tr = v.x * wc + v.y * wsn;     // v * conj(w)
        double ti2 = v.y * wc - v.x * wsn;
        double2 p0, p1;
        p0.x = u.x + tr; p0.y = u.y + ti2;
        p1.x = u.x - tr; p1.y = u.y - ti2;
        c[pa] = p0;
        c[pb] = p1;
        __syncthreads();
    }

    #pragma unroll
    for (int h = 0; h < 2; ++h) {
        int t = tid + h * 1024;
        double2 v = c[CP(t)];
        a_t[base + t] = (float)sqrt(v.x * v.x + v.y * v.y);
        p_t[base + t] = (float)atan2(v.y, v.x);
    }
}

// ======================================================================
// K3: MERGED poly + tail -> y_hat directly (part round-trip eliminated).
//   512 compute blocks x 64 points; thread = (point pi=tid>>2, l-group
//   lg=tid&3 -> l in [lg*4, lg*4+4)). All 968 features in one straight-
//   line body; 8 SEPARATE per-slice accumulators s[8][4] (compile-time
//   indexed: d literal after unroll) reproduce K3a's per-slice fmaf
//   chains EXACTLY; epilogue acc = bias + s0 + ... + s7 + amp + phase
//   reproduces K3b's add order EXACTLY -> bit-identical y_hat.
//   LDS: 15488 f poly weights + 512 f amp/phase = 64000 B (2 blocks/CU,
//   same occupancy as old K3a). Blocks >=512: jac range R3 (unchanged).
// ======================================================================
#define EMITF(EXPR) do {                                                    \
    float fv = (EXPR);                                                      \
    _Pragma("unroll") for (int l = 0; l < 4; ++l)                           \
        s[d / 121][l] = fmaf(fv, lw[(d << 4) + lg4 + l], s[d / 121][l]);    \
    ++d;                                                                    \
} while (0)

__global__ __launch_bounds__(256, 2) void k3_merged(
    const float* __restrict__ z_ws, const float* __restrict__ wt,
    const float* __restrict__ a_t, const float* __restrict__ p_t,
    const float* __restrict__ bsin, const float* __restrict__ Wenc,
    float* __restrict__ out_y, float* __restrict__ out_jac)
{
    __shared__ float lw[15488];               // 968 features x 16
    __shared__ float lw2[512];                // rows 984..1015 (amp | phase)
    int tid = threadIdx.x;
    if (blockIdx.x >= 512) {                  // 1024 writer blocks, nth = 262144
        jac_range(Wenc, out_jac, R3_LO, R3_HI, (blockIdx.x - 512) * 256 + tid, 262144);
        return;
    }

    {   // stage all poly weights (3872 f4) + amp/phase rows (128 f4)
        const float4* src = (const float4*)wt;
        float4* dst = (float4*)lw;
        for (int i = tid; i < 3872; i += 256) dst[i] = src[i];
        if (tid < 128) ((float4*)lw2)[tid] = src[3936 + tid];   // wt + 984*16
    }
    __syncthreads();

    int pi  = tid >> 2;                       // 0..63
    int lg4 = (tid & 3) * 4;                  // l-group base
    int bt  = blockIdx.x * 64 + pi;

    float z[16];
    {
        const float4* zp = (const float4*)(z_ws + (size_t)bt * 16);
        #pragma unroll
        for (int q = 0; q < 4; ++q) {
            float4 v = zp[q];
            z[q*4+0]=v.x; z[q*4+1]=v.y; z[q*4+2]=v.z; z[q*4+3]=v.w;
        }
    }

    float s[8][4];
    #pragma unroll
    for (int sl = 0; sl < 8; ++sl)
        #pragma unroll
        for (int l = 0; l < 4; ++l) s[sl][l] = 0.f;

    int d = 0;
    #pragma unroll
    for (int i = 0; i < 16; ++i) EMITF(z[i]);                              // deg 1 (folded)
    #pragma unroll
    for (int i = 0; i < 16; ++i)
        #pragma unroll
        for (int j = i; j < 16; ++j) EMITF(z[i] * z[j]);                   // deg 2
    #pragma unroll
    for (int i = 0; i < 16; ++i)
        #pragma unroll
        for (int j = i; j < 16; ++j)
            #pragma unroll
            for (int k = j; k < 16; ++k) EMITF(z[i] * z[j] * z[k]);        // deg 3

    // ---- tail: EXACT K3b order: bias, +s0..+s7, amp, phase ----
    float acc[4];
    #pragma unroll
    for (int l = 0; l < 4; ++l) acc[l] = bsin[lg4 + l];
    #pragma unroll
    for (int sl = 0; sl < 8; ++sl)
        #pragma unroll
        for (int l = 0; l < 4; ++l) acc[l] += s[sl][l];
    #pragma unroll
    for (int i = 0; i < 16; ++i) {
        float av = a_t[(size_t)i * 32768 + bt];
        #pragma unroll
        for (int l = 0; l < 4; ++l) acc[l] = fmaf(av, lw2[i * 16 + lg4 + l], acc[l]);
    }
    #pragma unroll
    for (int i = 0; i < 16; ++i) {
        float pv = p_t[(size_t)i * 32768 + bt];
        #pragma unroll
        for (int l = 0; l < 4; ++l) acc[l] = fmaf(pv, lw2[256 + i * 16 + lg4 + l], acc[l]);
    }

    float4 v;
    v.x = acc[0]; v.y = acc[1]; v.z = acc[2]; v.w = acc[3];
    *(float4*)(out_y + (size_t)bt * 16 + lg4) = v;
}

// ======================================================================
extern "C" void kernel_launch(void* const* d_in, const int* in_sizes, int n_in,
                              void* d_out, int out_size, void* d_ws, size_t ws_size,
                              hipStream_t stream)
{
    const float* x  = (const float*)d_in[0];
    const float* We = (const float*)d_in[1];
    const float* be = (const float*)d_in[2];
    const float* Wd = (const float*)d_in[3];
    const float* bd = (const float*)d_in[4];
    const float* Ws = (const float*)d_in[5];
    const float* bs = (const float*)d_in[6];

    float* out  = (float*)d_out;
    float* o_y  = out;                 // [16,2048,16]
    float* o_xh = out + 524288;        // [16,2048,128]
    float* o_z  = out + 4718592;       // [16,2048,16]
    float* o_j  = out + 5242880;       // [16,2048,16,128]  (268 MB)
    float* o_Ws = out + 72351744;      // [16,1016]
    float* o_Wd = out + 72368000;      // [128,16]

    float*  ws    = (float*)d_ws;
    float*  a_t   = ws + OFF_AT;
    float*  p_t   = ws + OFF_PT;
    float*  wt    = ws + OFF_WT;
    float*  z_t   = ws + OFF_ZT;
    double* twc_g = (double*)(ws + OFF_TWC);
    double* tws_g = (double*)(ws + OFF_TWS);

    hipLaunchKernelGGL(k1_encdec, dim3(2116), dim3(256), 0, stream,
                       x, We, be, Wd, bd, Ws, o_z, o_xh, o_Ws, o_Wd,
                       z_t, wt, twc_g, tws_g, o_j);
    hipLaunchKernelGGL(k2_hilbert, dim3(768), dim3(1024), 0, stream,
                       z_t, twc_g, tws_g, We, a_t, p_t, o_j);
    hipLaunchKernelGGL(k3_merged, dim3(1536), dim3(256), 0, stream,
                       o_z, wt, a_t, p_t, bs, We, o_y, o_j);
}